// Round 13
// baseline (307.785 us; speedup 1.0000x reference)
//
#include <hip/hip_runtime.h>
#include <math.h>

#define NN   24          // nodes per graph
#define EPB  16          // graph elements per block
#define CSTR 28          // LDS column stride (floats): 24 + 4 pad, 16B aligned
#define ESTR 452         // per-elem stride: 16*28 + 4 → e-stride ≡ 4 banks mod 32
#define T    256         // prep kernel block size
#define TM   128         // main kernel block size: 8 threads/elem halves LDS reads

typedef float v2f __attribute__((ext_vector_type(2)));

// ws layout (floats): [0..575] A(24x24) | [576..2111] Wc(768x2) | [2112..2113] bc(2)

__global__ void prep_kernel(const int* __restrict__ ei, int ec,
                            const float* __restrict__ fcw1, const float* __restrict__ fcb1,
                            const float* __restrict__ fcw2, const float* __restrict__ fcb2,
                            float* __restrict__ ws) {
  int t = threadIdx.x;
  if (blockIdx.x == 0) {
    __shared__ float deg[NN];
    __shared__ float dinv[NN];
    __shared__ float As[NN*NN];
    __shared__ int s_is64;
    if (t == 0) s_is64 = 1;
    if (t < NN) deg[t] = 1.0f;            // self-loop contribution
    for (int k = t; k < NN*NN; k += T) As[k] = 0.0f;
    __syncthreads();
    // dtype sniff: int64 edge_index viewed as int32 has all odd (high) words == 0
    for (int k = t; k < 2*ec; k += T) {
      if (ei[2*k + 1] != 0) atomicExch(&s_is64, 0);
    }
    __syncthreads();
    int is64 = s_is64;
    for (int k = t; k < ec; k += T) {
      int d = is64 ? ei[2*(ec + k)] : ei[ec + k];
      atomicAdd(&deg[d], 1.0f);
    }
    __syncthreads();
    if (t < NN) dinv[t] = 1.0f / sqrtf(deg[t]);
    __syncthreads();
    for (int k = t; k < ec; k += T) {
      int s = is64 ? ei[2*k]        : ei[k];
      int d = is64 ? ei[2*(ec + k)] : ei[ec + k];
      atomicAdd(&As[d*NN + s], dinv[s]*dinv[d]);
    }
    if (t < NN) atomicAdd(&As[t*NN + t], dinv[t]*dinv[t]);  // self loop
    __syncthreads();
    for (int k = t; k < NN*NN; k += T) ws[k] = As[k];
    if (t < 2) {
      float acc = fcb2[t];
      for (int k = 0; k < 128; ++k) acc += fcb1[k]*fcw2[k*2 + t];
      ws[2112 + t] = acc;
    }
  } else {
    // Wc = fcw1 @ fcw2 : blocks 1..8 compute 96 rows each
    int r0 = (blockIdx.x - 1) * 96;
    for (int idx = t; idx < 96*2; idx += T) {
      int r = r0 + (idx >> 1), c = idx & 1;
      float acc = 0.f;
      for (int k = 0; k < 128; ++k) acc += fcw1[r*128 + k]*fcw2[k*2 + c];
      ws[576 + r*2 + c] = acc;
    }
  }
}

// Feature-paired merged step: gbuf holds g_l (FIN cols per elem). Thread owns a
// COLUMN-PAIR (f, f+1) of one elem: hh[i] = (h[i][f], h[i][f+1]) — one read of
// the g-column serves two outputs (halved LDS-issue vs one-col tasks).
// W-mix (pk-fma) → relu → BARRIER → A-mix per row-pair (A scalar, wave-uniform
// → s_load) → float2 writes into both columns in place.
template<int FIN, int FOUT, int SPLIT>
__device__ __forceinline__ void merged_fp(const float* __restrict__ Ag, float* gbuf,
                                          const float* Ws, const float* bs, int t) {
  constexpr int FP = FOUT/2;            // feature-pairs per elem
  constexpr int NT = EPB*FP;            // tasks: 32/32/64/64/128/128
  constexpr int CL = NN/SPLIT;          // 6/6/12/12/24/24
  int task  = t & (NT - 1);
  int chunk = t / NT;
  int i0;
  if constexpr (NT >= 64) i0 = __builtin_amdgcn_readfirstlane(chunk*CL);  // wave-uniform
  else                    i0 = chunk*CL;
  int e = task / FP;
  int f = (task % FP) * 2;
  const float* ib = gbuf + e*ESTR;
  float2 bb = *(const float2*)(bs + f);
  v2f hh[NN];
  #pragma unroll
  for (int i = 0; i < NN; ++i) hh[i] = (v2f){bb.x, bb.y};
  #pragma unroll
  for (int fi = 0; fi < FIN; ++fi) {
    float2 wp = *(const float2*)(Ws + fi*FOUT + f);
    v2f w2 = (v2f){wp.x, wp.y};
    const float4* c4 = (const float4*)(ib + fi*CSTR);
    #pragma unroll
    for (int k = 0; k < 6; ++k) {
      float4 v = c4[k];
      hh[4*k+0] = (v2f){v.x, v.x}*w2 + hh[4*k+0];   // v_pk_fma_f32
      hh[4*k+1] = (v2f){v.y, v.y}*w2 + hh[4*k+1];
      hh[4*k+2] = (v2f){v.z, v.z}*w2 + hh[4*k+2];
      hh[4*k+3] = (v2f){v.w, v.w}*w2 + hh[4*k+3];
    }
  }
  {
    v2f z2 = (v2f){0.f, 0.f};
    #pragma unroll
    for (int i = 0; i < NN; ++i) hh[i] = __builtin_elementwise_max(hh[i], z2);
  }
  __syncthreads();           // all gbuf reads complete before in-place overwrite
  float* colA = gbuf + e*ESTR + f*CSTR;
  float* colB = colA + CSTR;
  #pragma unroll
  for (int ii = 0; ii < CL; ii += 2) {
    int iA = i0 + ii;
    const float* ArA = Ag + iA*NN;        // wave-uniform rows → s_load
    const float* ArB = ArA + NN;
    v2f a0 = (v2f){0.f, 0.f}, a1 = (v2f){0.f, 0.f};
    #pragma unroll
    for (int j = 0; j < NN; ++j) {
      a0 = (v2f){ArA[j], ArA[j]}*hh[j] + a0;
      a1 = (v2f){ArB[j], ArB[j]}*hh[j] + a1;
    }
    *(float2*)(colA + iA) = make_float2(a0.x, a1.x);
    *(float2*)(colB + iA) = make_float2(a0.y, a1.y);
  }
}

// (128,2): relaxed bound so the allocator grants the ~70-VGPR live set
// (hh[24] v2f = 48 floats). Tight bounds clamp to 48-64 and spill (R2-R9).
__global__ __launch_bounds__(TM, 2) void gcn_main(
    const float* __restrict__ x, const float* __restrict__ ws,
    const float* __restrict__ W1, const float* __restrict__ b1,
    const float* __restrict__ W2, const float* __restrict__ b2,
    const float* __restrict__ W3, const float* __restrict__ b3,
    const float* __restrict__ W4, const float* __restrict__ b4,
    const float* __restrict__ W5, const float* __restrict__ b5,
    const float* __restrict__ W6, const float* __restrict__ b6,
    const float* __restrict__ W7, const float* __restrict__ b7,
    float* __restrict__ out) {
  __shared__ __align__(16) float gbuf[EPB*ESTR];  // 28928 B, single in-place buffer
  __shared__ __align__(16) float Wsh[500];        // W1..W6; W7 read from global/L1
  __shared__ __align__(16) float bsh[88];
  int t = threadIdx.x;

  // stage layer weights/biases into LDS
  {
    const float* Wp[6] = {W1,W2,W3,W4,W5,W6};
    const float* bp[7] = {b1,b2,b3,b4,b5,b6,b7};
    const int wsz[6] = {4,16,32,64,128,256};
    const int wof[6] = {0,4,20,52,116,244};
    const int bsz[7] = {4,4,8,8,16,16,32};
    const int bof[7] = {0,4,8,16,24,40,56};
    #pragma unroll
    for (int l = 0; l < 6; ++l) {
      for (int k = t; k < wsz[l]; k += TM) Wsh[wof[l] + k] = Wp[l][k];
    }
    #pragma unroll
    for (int l = 0; l < 7; ++l) {
      if (t < bsz[l]) bsh[bof[l] + t] = bp[l][t];
    }
  }
  // stage x tile into column slot 1 of each elem (col 0 gets g1 = A@x)
  {
    const float* xg = x + (size_t)blockIdx.x * (EPB*NN);
    if (t < EPB*NN/4) {
      float4 v = ((const float4*)xg)[t];
      int e = t/6, k = t - e*6;
      ((float4*)(gbuf + e*ESTR + CSTR))[k] = v;
    }
  }
  __syncthreads();

  // g1 = A @ x : 384 tasks (e, i) over 3 iterations of 128 threads
  #pragma unroll
  for (int it = 0; it < 3; ++it) {
    int idx = t + it*TM;
    int e = idx & 15, i = idx >> 4;
    const float4* xv = (const float4*)(gbuf + e*ESTR + CSTR);
    const float4* Ar = (const float4*)(ws + i*NN);
    float acc = 0.f;
    #pragma unroll
    for (int k = 0; k < 6; ++k) {
      float4 a = Ar[k]; float4 v = xv[k];
      acc += a.x*v.x + a.y*v.y + a.z*v.z + a.w*v.w;
    }
    gbuf[e*ESTR + i] = acc;
  }
  __syncthreads();

  merged_fp<1, 4, 4>(ws, gbuf, Wsh+0,   bsh+0,  t); __syncthreads();
  merged_fp<4, 4, 4>(ws, gbuf, Wsh+4,   bsh+4,  t); __syncthreads();
  merged_fp<4, 8, 2>(ws, gbuf, Wsh+20,  bsh+8,  t); __syncthreads();
  merged_fp<8, 8, 2>(ws, gbuf, Wsh+52,  bsh+16, t); __syncthreads();
  merged_fp<8,16, 1>(ws, gbuf, Wsh+116, bsh+24, t); __syncthreads();
  merged_fp<16,16,1>(ws, gbuf, Wsh+244, bsh+40, t); __syncthreads();

  // L7 + composed FC + log_softmax. L7 has NO A-mix, so tasks can row-chunk:
  // 16 tasks/elem = 8 f-quads x 2 row-halves; each task reads only 12 rows x
  // 16 cols of g7 (48 b128 — 4x less than a full-tile task) and computes a
  // 12x4 h7 tile (2 v2f arrays), relu, partial (p0,p1), 16-lane butterfly.
  {
    const float* Wc = ws + 576;
    float bc0 = ws[2112], bc1 = ws[2113];
    v2f z2 = (v2f){0.f, 0.f};
    #pragma unroll
    for (int r = 0; r < 2; ++r) {
      int e   = (t >> 4) + r*8;        // elems 0..7 then 8..15
      int sub = t & 15;
      int f0  = (sub >> 1) * 4;        // 0,4,...,28
      int i0  = (sub & 1) * 12;        // 0 or 12
      const float* ib = gbuf + e*ESTR + i0;
      float4 b4v = *(const float4*)(bsh + 56 + f0);
      v2f hA[12], hB[12];
      #pragma unroll
      for (int j = 0; j < 12; ++j) { hA[j] = (v2f){b4v.x, b4v.y}; hB[j] = (v2f){b4v.z, b4v.w}; }
      #pragma unroll
      for (int fi = 0; fi < 16; ++fi) {
        const float4* cp = (const float4*)(ib + fi*CSTR);
        float4 w4 = *(const float4*)(W7 + fi*32 + f0);   // global, L1-hot
        v2f wab = (v2f){w4.x, w4.y}, wcd = (v2f){w4.z, w4.w};
        #pragma unroll
        for (int k = 0; k < 3; ++k) {
          float4 v = cp[k];
          float gj[4] = {v.x, v.y, v.z, v.w};
          #pragma unroll
          for (int q = 0; q < 4; ++q) {
            int j = 4*k + q;
            v2f gb = (v2f){gj[q], gj[q]};
            hA[j] = gb*wab + hA[j];
            hB[j] = gb*wcd + hB[j];
          }
        }
      }
      v2f p = (v2f){0.f, 0.f};         // (p0, p1)
      #pragma unroll
      for (int j = 0; j < 12; ++j) {
        int i = i0 + j;
        v2f ha = __builtin_elementwise_max(hA[j], z2);
        v2f hb = __builtin_elementwise_max(hB[j], z2);
        float4 c01 = *(const float4*)(Wc + (i*32 + f0)*2);      // feats f0, f0+1
        float4 c23 = *(const float4*)(Wc + (i*32 + f0 + 2)*2);  // feats f0+2, f0+3
        p = (v2f){ha.x, ha.x}*(v2f){c01.x, c01.y} + p;
        p = (v2f){ha.y, ha.y}*(v2f){c01.z, c01.w} + p;
        p = (v2f){hb.x, hb.x}*(v2f){c23.x, c23.y} + p;
        p = (v2f){hb.y, hb.y}*(v2f){c23.z, c23.w} + p;
      }
      float p0 = p.x, p1 = p.y;
      #pragma unroll
      for (int m = 1; m < 16; m <<= 1) {
        p0 += __shfl_xor(p0, m, 16);
        p1 += __shfl_xor(p1, m, 16);
      }
      if (sub == 0) {
        float z0 = p0 + bc0, z1 = p1 + bc1;
        float mx = fmaxf(z0, z1);
        float lse = mx + logf(expf(z0 - mx) + expf(z1 - mx));
        int eg = blockIdx.x*EPB + e;
        *(float2*)(out + eg*2) = make_float2(z0 - lse, z1 - lse);
      }
    }
  }
}

extern "C" void kernel_launch(void* const* d_in, const int* in_sizes, int n_in,
                              void* d_out, int out_size, void* d_ws, size_t ws_size,
                              hipStream_t stream) {
  const float* x    = (const float*)d_in[0];
  const int*   ei   = (const int*)  d_in[1];
  const float* W1   = (const float*)d_in[2];  const float* b1 = (const float*)d_in[3];
  const float* W2   = (const float*)d_in[4];  const float* b2 = (const float*)d_in[5];
  const float* W3   = (const float*)d_in[6];  const float* b3 = (const float*)d_in[7];
  const float* W4   = (const float*)d_in[8];  const float* b4 = (const float*)d_in[9];
  const float* W5   = (const float*)d_in[10]; const float* b5 = (const float*)d_in[11];
  const float* W6   = (const float*)d_in[12]; const float* b6 = (const float*)d_in[13];
  const float* W7   = (const float*)d_in[14]; const float* b7 = (const float*)d_in[15];
  const float* fcw1 = (const float*)d_in[16]; const float* fcb1 = (const float*)d_in[17];
  const float* fcw2 = (const float*)d_in[18]; const float* fcb2 = (const float*)d_in[19];
  float* out = (float*)d_out;
  float* ws  = (float*)d_ws;
  int ec = in_sizes[1] / 2;        // 96 edges
  int B  = in_sizes[0] / NN;       // 32768

  hipLaunchKernelGGL(prep_kernel, dim3(9), dim3(T), 0, stream,
                     ei, ec, fcw1, fcb1, fcw2, fcb2, ws);
  hipLaunchKernelGGL(gcn_main, dim3(B/EPB), dim3(TM), 0, stream,
                     x, ws, W1,b1, W2,b2, W3,b3, W4,b4, W5,b5, W6,b6, W7,b7, out);
}